// Round 10
// baseline (249.972 us; speedup 1.0000x reference)
//
#include <hip/hip_runtime.h>
#include <hip/hip_bf16.h>

typedef __attribute__((ext_vector_type(8))) short bf16x8;
typedef __attribute__((ext_vector_type(4))) float f32x4;
typedef unsigned short u16;

#define S_LEN 4096
#define DM 1024
#define NH 16
#define DH 64
#define PSTR 72

// manual RNE fp32->bf16 (inputs never NaN here): 3 VALU ops
__device__ __forceinline__ u16 f2b_rne(float f) {
  unsigned u = __builtin_bit_cast(unsigned, f);
  return (u16)((u + 0x7fffu + ((u >> 16) & 1u)) >> 16);
}
// pack two fp32 -> bf16x2 in one u32 (RNE)
__device__ __forceinline__ unsigned pk2(float a, float b) {
  unsigned ua = __builtin_bit_cast(unsigned, a);
  unsigned ub = __builtin_bit_cast(unsigned, b);
  ua = (ua + 0x7fffu + ((ua >> 16) & 1u)) >> 16;
  ub = (ub + 0x7fffu + ((ub >> 16) & 1u)) & 0xffff0000u;
  return ua | ub;
}
// pack two fp32 -> bf16x2, TRUNCATED: single v_perm_b32.
// bias cancels in softmax (same P in numerator and denominator).
__device__ __forceinline__ unsigned pk2t(float a, float b) {
  return __builtin_amdgcn_perm(__builtin_bit_cast(unsigned, b),
                               __builtin_bit_cast(unsigned, a), 0x07060302u);
}

// global -> LDS direct (16B per lane; lds base must be wave-uniform)
__device__ __forceinline__ void glds16(const u16* g, u16* l) {
  __builtin_amdgcn_global_load_lds(
      (const __attribute__((address_space(1))) unsigned int*)g,
      (__attribute__((address_space(3))) unsigned int*)l, 16, 0, 0);
}

// ---------------- fp32 -> bf16, all 5 inputs in one launch ----------------
__global__ __launch_bounds__(256) void cvt_all(const float* __restrict__ x,
                                               const float* __restrict__ Wq,
                                               const float* __restrict__ Wk,
                                               const float* __restrict__ Wv,
                                               const float* __restrict__ Wo,
                                               u16* __restrict__ xb, u16* __restrict__ wqb,
                                               u16* __restrict__ wkb, u16* __restrict__ wvb,
                                               u16* __restrict__ wob) {
  int idx = (blockIdx.x * 256 + threadIdx.x) * 4;
  const float* src;
  u16* dst;
  int o;
  if (idx < 4194304) {
    src = x; dst = xb; o = idx;
  } else {
    int t = idx - 4194304;
    int wsel = t >> 20;
    o = t & 1048575;
    src = (wsel == 0) ? Wq : (wsel == 1) ? Wk : (wsel == 2) ? Wv : Wo;
    dst = (wsel == 0) ? wqb : (wsel == 1) ? wkb : (wsel == 2) ? wvb : wob;
  }
  float4 v = *(const float4*)(src + o);
  uint2 ov;
  ov.x = pk2(v.x, v.y);
  ov.y = pk2(v.z, v.w);
  *(uint2*)(dst + o) = ov;
}

// ---------------- zero the O/L accumulators (fallback path only) -----------
__global__ __launch_bounds__(256) void zero_kernel(float4* __restrict__ p) {
  p[blockIdx.x * 256 + threadIdx.x] = float4{0.f, 0.f, 0.f, 0.f};
}

// ---------------- fused QKV NT-GEMM with RoPE epilogue; V written transposed
// grid (24, 32): mat = bx>>3 (0=Q rope+scale, 1=K rope, 2=V -> Vt), nb = (bx&7)*128
__global__ __launch_bounds__(256) void qkv_gemm(const u16* __restrict__ A,
                                                const u16* __restrict__ Wq,
                                                const u16* __restrict__ Wk,
                                                const u16* __restrict__ Wv,
                                                u16* __restrict__ Qo, u16* __restrict__ Ko,
                                                u16* __restrict__ Vt) {
  __shared__ __align__(16) u16 As[2 * 128 * 32];
  __shared__ __align__(16) u16 Bs[2 * 128 * 32];
  const int mat = blockIdx.x >> 3;
  const u16* B = (mat == 0) ? Wq : (mat == 1) ? Wk : Wv;
  const int K = DM, N = DM;
  const int tid = threadIdx.x;
  const int wave = tid >> 6, lane = tid & 63;
  const int fm = lane & 15, fq = lane >> 4;
  const int mb = blockIdx.y * 128, nb = (blockIdx.x & 7) * 128;
  const int wm = (wave & 1) * 64, wn = (wave >> 1) * 64;

  f32x4 acc[4][4];
#pragma unroll
  for (int i = 0; i < 4; ++i)
#pragma unroll
    for (int j = 0; j < 4; ++j)
#pragma unroll
      for (int r = 0; r < 4; ++r) acc[i][j][r] = 0.f;

  const int r_ = tid >> 2;
  const int cg = (tid & 3) ^ ((r_ >> 1) & 3);
  const u16* Ag0 = A + (size_t)(mb + r_) * K + cg * 8;
  const u16* Ag1 = A + (size_t)(mb + r_ + 64) * K + cg * 8;
  const u16* Bg0 = B + (size_t)(nb + r_) * K + cg * 8;
  const u16* Bg1 = B + (size_t)(nb + r_ + 64) * K + cg * 8;
  const int l0 = wave * 512;
  const int l1 = 2048 + wave * 512;
  const int sw = (fm >> 1) & 3;

  int buf = 0;
  glds16(Ag0, As + l0);
  glds16(Ag1, As + l1);
  glds16(Bg0, Bs + l0);
  glds16(Bg1, Bs + l1);

  for (int k0 = 0; k0 < K; k0 += 32) {
    __syncthreads();
    if (k0 + 32 < K) {
      int bo = (buf ^ 1) * 4096;
      glds16(Ag0 + k0 + 32, As + bo + l0);
      glds16(Ag1 + k0 + 32, As + bo + l1);
      glds16(Bg0 + k0 + 32, Bs + bo + l0);
      glds16(Bg1 + k0 + 32, Bs + bo + l1);
    }
    const u16* Ab = As + buf * 4096;
    const u16* Bb = Bs + buf * 4096;
    bf16x8 av[4], bv[4];
#pragma unroll
    for (int t = 0; t < 4; ++t) {
      av[t] = *(const bf16x8*)(Ab + (wm + t * 16 + fm) * 32 + ((fq ^ sw) * 8));
      bv[t] = *(const bf16x8*)(Bb + (wn + t * 16 + fm) * 32 + ((fq ^ sw) * 8));
    }
#pragma unroll
    for (int i = 0; i < 4; ++i)
#pragma unroll
      for (int j = 0; j < 4; ++j)
        acc[i][j] = __builtin_amdgcn_mfma_f32_16x16x32_bf16(av[i], bv[j], acc[i][j], 0, 0, 0);
    buf ^= 1;
  }

  if (mat < 2) {
    // RoPE epilogue (in-register): pairs (d, d+32) = regs (j, j+2), d = j*16+fm, j in {0,1}
    u16* Out = (mat == 0) ? Qo : Ko;
    const float qs = (mat == 0) ? 0.1803368801111204f : 1.0f;  // 0.125*log2(e) for Q
    const float c1 = -9.2103403719761836f / 32.f;              // -ln(10000)/32
    const float if0 = __expf((float)fm * c1);
    const float if1 = __expf((float)(16 + fm) * c1);
#pragma unroll
    for (int ii = 0; ii < 4; ++ii) {
#pragma unroll
      for (int r = 0; r < 4; ++r) {
        float s = (float)(mb + wm + ii * 16 + fq * 4 + r);
#pragma unroll
        for (int jp = 0; jp < 2; ++jp) {
          float ang = s * (jp ? if1 : if0);
          float sn, cs;
          __sincosf(ang, &sn, &cs);
          float a = acc[ii][jp][r], b = acc[ii][jp + 2][r];
          acc[ii][jp][r] = (a * cs - b * sn) * qs;
          acc[ii][jp + 2][r] = (b * cs + a * sn) * qs;
        }
      }
    }
#pragma unroll
    for (int i = 0; i < 4; ++i)
#pragma unroll
      for (int j = 0; j < 4; ++j)
#pragma unroll
        for (int r = 0; r < 4; ++r) {
          int row = mb + wm + i * 16 + fq * 4 + r;
          int col = nb + wn + j * 16 + fm;
          Out[(size_t)row * N + col] = f2b_rne(acc[i][j][r]);
        }
  } else {
    // V: write transposed Vt[col][row]; 4 r-values are contiguous rows -> 8B store
#pragma unroll
    for (int i = 0; i < 4; ++i)
#pragma unroll
      for (int j = 0; j < 4; ++j) {
        int col = nb + wn + j * 16 + fm;
        int row0 = mb + wm + i * 16 + fq * 4;
        uint2 pv;
        pv.x = pk2(acc[i][j][0], acc[i][j][1]);
        pv.y = pk2(acc[i][j][2], acc[i][j][3]);
        *(uint2*)(Vt + (size_t)col * S_LEN + row0) = pv;
      }
  }
}

// ---------------- O-projection NT GEMM, 64x128 tiles (fp32 out) -------------
// grid (8, 64): nb = bx*128, mb = by*64. 512 blocks -> real occupancy (vs 256).
__global__ __launch_bounds__(256) void o_gemm(const u16* __restrict__ A,
                                              const u16* __restrict__ B,
                                              float* __restrict__ C, int M, int N, int K) {
  __shared__ __align__(16) u16 As[2 * 64 * 32];
  __shared__ __align__(16) u16 Bs[2 * 128 * 32];
  const int tid = threadIdx.x;
  const int wave = tid >> 6, lane = tid & 63;
  const int fm = lane & 15, fq = lane >> 4;
  const int mb = blockIdx.y * 64, nb = blockIdx.x * 128;
  const int wm = (wave & 1) * 32, wn = (wave >> 1) * 64;

  f32x4 acc[2][4];
#pragma unroll
  for (int i = 0; i < 2; ++i)
#pragma unroll
    for (int j = 0; j < 4; ++j)
#pragma unroll
      for (int r = 0; r < 4; ++r) acc[i][j][r] = 0.f;

  const int r_ = tid >> 2;
  const int cg = (tid & 3) ^ ((r_ >> 1) & 3);
  const u16* Ag0 = A + (size_t)(mb + r_) * K + cg * 8;
  const u16* Bg0 = B + (size_t)(nb + r_) * K + cg * 8;
  const u16* Bg1 = B + (size_t)(nb + r_ + 64) * K + cg * 8;
  const int l0 = wave * 512;
  const int l1 = 2048 + wave * 512;
  const int sw = (fm >> 1) & 3;

  int buf = 0;
  glds16(Ag0, As + l0);
  glds16(Bg0, Bs + l0);
  glds16(Bg1, Bs + l1);

  for (int k0 = 0; k0 < K; k0 += 32) {
    __syncthreads();
    if (k0 + 32 < K) {
      int aoff = (buf ^ 1) * 2048, boff = (buf ^ 1) * 4096;
      glds16(Ag0 + k0 + 32, As + aoff + l0);
      glds16(Bg0 + k0 + 32, Bs + boff + l0);
      glds16(Bg1 + k0 + 32, Bs + boff + l1);
    }
    const u16* Ab = As + buf * 2048;
    const u16* Bb = Bs + buf * 4096;
    bf16x8 av[2], bv[4];
#pragma unroll
    for (int t = 0; t < 2; ++t)
      av[t] = *(const bf16x8*)(Ab + (wm + t * 16 + fm) * 32 + ((fq ^ sw) * 8));
#pragma unroll
    for (int t = 0; t < 4; ++t)
      bv[t] = *(const bf16x8*)(Bb + (wn + t * 16 + fm) * 32 + ((fq ^ sw) * 8));
#pragma unroll
    for (int i = 0; i < 2; ++i)
#pragma unroll
      for (int j = 0; j < 4; ++j)
        acc[i][j] = __builtin_amdgcn_mfma_f32_16x16x32_bf16(av[i], bv[j], acc[i][j], 0, 0, 0);
    buf ^= 1;
  }
#pragma unroll
  for (int i = 0; i < 2; ++i)
#pragma unroll
    for (int j = 0; j < 4; ++j)
#pragma unroll
      for (int r = 0; r < 4; ++r) {
        int row = mb + wm + i * 16 + fq * 4 + r;
        int col = nb + wn + j * 16 + fm;
        C[(size_t)row * N + col] = acc[i][j][r];
      }
}

// ---------------- causal flash attention v15: v10 + ablation variant -------
// ABL=0: EXACT round-4 v10 (best measured: 78.6 us attn; setprio reverted).
// ABL=1: FRONT-END ONLY — staging + barriers + prefetch + K ds_reads +
// QK^T MFMAs + mask kept; exp2/pack/Ps-roundtrip/pvb/PV removed; st kept
// live by folding into o (rule #17: no DCE of upstream QK^T/staging).
// The ablation dispatch runs BEFORE the real one, writing garbage to
// Op/Lp; the real dispatch overwrites every element (STORE path writes
// unconditionally) -> correctness preserved. F = headline - 220 us
// measures the front-end floor: F>=55 -> lockstep/staging is the wall;
// F<=35 -> the per-wave softmax serial chain is the wall.
template <int STORE, int ABL>
__global__ __launch_bounds__(512, 4) void attn_kernel(const u16* __restrict__ Q,
                                                      const u16* __restrict__ K,
                                                      const u16* __restrict__ Vt,
                                                      float* __restrict__ Oacc,
                                                      float* __restrict__ Lacc) {
  __shared__ __align__(16) u16 Ks[2 * 4096];   // 2 x (64 key x 64 d), swizzled
  __shared__ __align__(16) u16 Vs[2 * 4096];   // 2 x (64 d x 64 key), swizzled
  __shared__ __align__(16) u16 Ps[8][16 * PSTR];  // per-wave, g-sequential
  const int tid = threadIdx.x;
  const int w = tid >> 6, lane = tid & 63;
  const int fm = lane & 15, fq = lane >> 4;
  const int bid = blockIdx.x;       // [0,512)
  const int u = bid & 255, hi = bid >> 8;
  const int h = u & 15;
  const int qt0 = u >> 4;           // [0,16)
  const int qt = hi ? qt0 : 15 - qt0;
  const int half = hi;
  const int qb = qt * 256 + w * 32;
  const int nlocal = 2 * qt + 2;    // tiles per half (total 4qt+4)
  const int kbase = half * nlocal;
  const int dtile = qb >> 6;        // == dtile: partial mask; > dtile: skip

  bf16x8 q0[2], q1[2];
#pragma unroll
  for (int g = 0; g < 2; ++g) {
    const u16* qp = Q + (size_t)(qb + g * 16 + fm) * DM + h * DH + fq * 8;
    q0[g] = *(const bf16x8*)(qp);
    q1[g] = *(const bf16x8*)(qp + 32);
  }
  f32x4 o[2][4];
  f32x4 ls[2];
#pragma unroll
  for (int g = 0; g < 2; ++g) {
#pragma unroll
    for (int r = 0; r < 4; ++r) ls[g][r] = 0.f;
#pragma unroll
    for (int c4 = 0; c4 < 4; ++c4)
#pragma unroll
      for (int r = 0; r < 4; ++r) o[g][c4][r] = 0.f;
  }
  const short ONEB = (short)0x3F80;  // 1.0 bf16
  const bf16x8 vone = {ONEB, ONEB, ONEB, ONEB, ONEB, ONEB, ONEB, ONEB};

  // staging: 512 slots x 16B = one full 64x64 tile; slot = tid.
  // row = tid>>3, stored chunk = tid&7, global chunk = (tid&7) ^ (row&7).
  const int rr = tid >> 3;                 // [0,64)
  const int cc8 = (tid & 7) ^ (rr & 7);
  const u16* Kg = K + (size_t)rr * DM + h * DH + cc8 * 8;
  const u16* Vg = Vt + (size_t)(h * DH + rr) * S_LEN + cc8 * 8;
  const int l0 = w * 512;                  // wave-uniform LDS base (u16)
  const int sw7 = fm & 7;
  const f32x4 zf = {0.f, 0.f, 0.f, 0.f};

  glds16(Kg + (size_t)kbase * 64 * DM, Ks + l0);
  glds16(Vg + kbase * 64, Vs + l0);

  int buf = 0;
  for (int kl = 0; kl < nlocal; ++kl) {
    const int ktg = kbase + kl;
    __syncthreads();
    if (kl + 1 < nlocal) {
      int bo = (buf ^ 1) * 4096;
      glds16(Kg + (size_t)(ktg + 1) * 64 * DM, Ks + bo + l0);
      glds16(Vg + (ktg + 1) * 64, Vs + bo + l0);
    }
    if (ktg <= dtile) {
      const u16* Kb = Ks + buf * 4096;
      const u16* Vb = Vs + buf * 4096;

      // S^T = K * Q^T : D[key][q]
      f32x4 st[2][4];
#pragma unroll
      for (int t = 0; t < 4; ++t) {
        const u16* kr = Kb + (t * 16 + fm) * 64;
        bf16x8 ka = *(const bf16x8*)(kr + ((fq ^ sw7) * 8));
        bf16x8 kb2 = *(const bf16x8*)(kr + (((fq + 4) ^ sw7) * 8));
#pragma unroll
        for (int g = 0; g < 2; ++g) {
          f32x4 s = __builtin_amdgcn_mfma_f32_16x16x32_bf16(ka, q0[g], zf, 0, 0, 0);
          st[g][t] = __builtin_amdgcn_mfma_f32_16x16x32_bf16(kb2, q1[g], s, 0, 0, 0);
        }
      }
      if (ktg == dtile) {  // diagonal tile: partial causal mask
#pragma unroll
        for (int g = 0; g < 2; ++g) {
          int qg = qb + g * 16 + fm;
#pragma unroll
          for (int t = 0; t < 4; ++t) {
            int key = ktg * 64 + t * 16 + fq * 4;
#pragma unroll
            for (int r = 0; r < 4; ++r)
              st[g][t][r] = (key + r > qg) ? -1e30f : st[g][t][r];
          }
        }
      }
      if (ABL) {
        // front-end ablation: fold st into o (keeps QK^T + staging live,
        // ~32 VALU adds/iter — negligible vs the phases being measured)
#pragma unroll
        for (int g = 0; g < 2; ++g)
#pragma unroll
          for (int t = 0; t < 4; ++t)
#pragma unroll
            for (int r = 0; r < 4; ++r) o[g][t][r] += st[g][t][r];
      } else {
        // V B-operand fragments (shared across g)
        bf16x8 pvb[4][2];
#pragma unroll
        for (int c4 = 0; c4 < 4; ++c4) {
          const u16* vr = Vb + (c4 * 16 + fm) * 64;
          pvb[c4][0] = *(const bf16x8*)(vr + ((fq ^ sw7) * 8));
          pvb[c4][1] = *(const bf16x8*)(vr + (((fq + 4) ^ sw7) * 8));
        }
        // g-sequential: exp2 -> pack -> LDS -> A-frag -> MFMAs, one g at a time
#pragma unroll
        for (int g = 0; g < 2; ++g) {
#pragma unroll
          for (int t = 0; t < 4; ++t) {
            float p0 = __builtin_amdgcn_exp2f(st[g][t][0]);
            float p1 = __builtin_amdgcn_exp2f(st[g][t][1]);
            float p2 = __builtin_amdgcn_exp2f(st[g][t][2]);
            float p3 = __builtin_amdgcn_exp2f(st[g][t][3]);
            uint2 pk;
            pk.x = pk2t(p0, p1);
            pk.y = pk2t(p2, p3);
            *(uint2*)(&Ps[w][fm * PSTR + t * 16 + fq * 4]) = pk;
          }
          asm volatile("s_waitcnt lgkmcnt(0)" ::: "memory");
          bf16x8 ap0 = *(const bf16x8*)(&Ps[w][fm * PSTR + fq * 8]);
          bf16x8 ap1 = *(const bf16x8*)(&Ps[w][fm * PSTR + 32 + fq * 8]);
          ls[g] = __builtin_amdgcn_mfma_f32_16x16x32_bf16(ap0, vone, ls[g], 0, 0, 0);
          ls[g] = __builtin_amdgcn_mfma_f32_16x16x32_bf16(ap1, vone, ls[g], 0, 0, 0);
#pragma unroll
          for (int c4 = 0; c4 < 4; ++c4) {
            o[g][c4] = __builtin_amdgcn_mfma_f32_16x16x32_bf16(ap0, pvb[c4][0], o[g][c4], 0, 0, 0);
            o[g][c4] = __builtin_amdgcn_mfma_f32_16x16x32_bf16(ap1, pvb[c4][1], o[g][c4], 0, 0, 0);
          }
        }
      }
    }
    buf ^= 1;
  }
  if (STORE) {
    // per-split partial stores: Opart[hi][h][row][d], Lpart[hi][h][row]
    float* Ob = Oacc + (((size_t)half * NH + h) * S_LEN + qt * 256 + w * 32) * DH;
    float* Lb = Lacc + ((size_t)half * NH + h) * S_LEN + qt * 256 + w * 32;
#pragma unroll
    for (int g = 0; g < 2; ++g) {
      if (fm == 0) {
#pragma unroll
        for (int r = 0; r < 4; ++r) Lb[g * 16 + fq * 4 + r] = ls[g][r];
      }
#pragma unroll
      for (int c4 = 0; c4 < 4; ++c4)
#pragma unroll
        for (int r = 0; r < 4; ++r)
          Ob[(size_t)(g * 16 + fq * 4 + r) * DH + c4 * 16 + fm] = o[g][c4][r];
    }
  } else {
    // fallback: atomic accumulate into shared Oacc/Lacc
    float* Ob = Oacc + ((size_t)h * S_LEN + qt * 256 + w * 32) * DH;
    float* Lb = Lacc + h * S_LEN + qt * 256 + w * 32;
#pragma unroll
    for (int g = 0; g < 2; ++g) {
      if (fm == 0) {
#pragma unroll
        for (int r = 0; r < 4; ++r)
          unsafeAtomicAdd(Lb + g * 16 + fq * 4 + r, ls[g][r]);
      }
#pragma unroll
      for (int c4 = 0; c4 < 4; ++c4)
#pragma unroll
        for (int r = 0; r < 4; ++r)
          unsafeAtomicAdd(Ob + (g * 16 + fq * 4 + r) * DH + c4 * 16 + fm, o[g][c4][r]);
    }
  }
}

// ---------------- combine (store path): Ctx = bf16((O0+O1) / (L0+L1)) ------
__global__ __launch_bounds__(256) void combine2_kernel(const float* __restrict__ O0,
                                                       const float* __restrict__ O1,
                                                       const float* __restrict__ L0,
                                                       const float* __restrict__ L1,
                                                       u16* __restrict__ Ctx) {
  int idx = blockIdx.x * 256 + threadIdx.x;  // 1,048,576 threads
  int d4 = (idx & 15) * 4;
  int hh = (idx >> 4) & 15;
  int row = idx >> 8;
  size_t ob = ((size_t)hh * S_LEN + row) * DH + d4;
  float4 a = *(const float4*)(O0 + ob);
  float4 b = *(const float4*)(O1 + ob);
  float il = 1.0f / (L0[hh * S_LEN + row] + L1[hh * S_LEN + row]);
  uint2 o;
  o.x = pk2((a.x + b.x) * il, (a.y + b.y) * il);
  o.y = pk2((a.z + b.z) * il, (a.w + b.w) * il);
  *(uint2*)(Ctx + (size_t)row * DM + hh * DH + d4) = o;
}

// ---------------- combine (atomic fallback): Ctx = bf16(Oacc / Lacc) --------
__global__ __launch_bounds__(256) void combine_kernel(const float* __restrict__ Oacc,
                                                      const float* __restrict__ Lacc,
                                                      u16* __restrict__ Ctx) {
  int idx = blockIdx.x * 256 + threadIdx.x;  // 1,048,576 threads
  int d4 = (idx & 15) * 4;
  int hh = (idx >> 4) & 15;
  int row = idx >> 8;
  float4 a = *(const float4*)(Oacc + ((size_t)hh * S_LEN + row) * DH + d4);
  float il = 1.0f / Lacc[hh * S_LEN + row];
  uint2 o;
  o.x = pk2(a.x * il, a.y * il);
  o.y = pk2(a.z * il, a.w * il);
  *(uint2*)(Ctx + (size_t)row * DM + hh * DH + d4) = o;
}

extern "C" void kernel_launch(void* const* d_in, const int* in_sizes, int n_in,
                              void* d_out, int out_size, void* d_ws, size_t ws_size,
                              hipStream_t stream) {
  const float* x  = (const float*)d_in[0];
  const float* Wq = (const float*)d_in[1];
  const float* Wk = (const float*)d_in[2];
  const float* Wv = (const float*)d_in[3];
  const float* Wo = (const float*)d_in[4];
  float* out = (float*)d_out;

  const size_t MB = 1u << 20;
  char* ws = (char*)d_ws;

  if (ws_size >= 72 * MB) {
    // store-path layout (72 MB):
    //  [0,8)   xb         -> Ctx (after attn)
    //  [8,14)  wqb/wkb/wvb -> Lpart [8,8.5) (after qkv)
    //  [14,16) wob (persists to o_gemm)
    //  [16,40) Qb, Kb, Vtb
    //  [40,72) Opart [2][16][4096][64] fp32
    u16* xb    = (u16*)(ws + 0 * MB);
    u16* wqb   = (u16*)(ws + 8 * MB);
    u16* wkb   = (u16*)(ws + 10 * MB);
    u16* wvb   = (u16*)(ws + 12 * MB);
    u16* wob   = (u16*)(ws + 14 * MB);
    u16* Qb    = (u16*)(ws + 16 * MB);
    u16* Kb    = (u16*)(ws + 24 * MB);
    u16* Vtb   = (u16*)(ws + 32 * MB);
    float* Op  = (float*)(ws + 40 * MB);
    float* Lp  = (float*)(ws + 8 * MB);
    u16* Ctx   = (u16*)(ws + 0 * MB);

    cvt_all<<<8192, 256, 0, stream>>>(x, Wq, Wk, Wv, Wo, xb, wqb, wkb, wvb, wob);
    qkv_gemm<<<dim3(24, 32), 256, 0, stream>>>(xb, wqb, wkb, wvb, Qb, Kb, Vtb);
    // ABLATION dispatch (front-end only; garbage into Op/Lp, fully
    // overwritten by the real dispatch below). F = headline - 220 us.
    attn_kernel<1, 1><<<512, 512, 0, stream>>>(Qb, Kb, Vtb, Op, Lp);
    // real attention (exact round-4 v10)
    attn_kernel<1, 0><<<512, 512, 0, stream>>>(Qb, Kb, Vtb, Op, Lp);
    combine2_kernel<<<4096, 256, 0, stream>>>(Op, Op + (size_t)NH * S_LEN * DH,
                                              Lp, Lp + (size_t)NH * S_LEN, Ctx);
    o_gemm<<<dim3(8, 64), 256, 0, stream>>>(Ctx, wob, out, S_LEN, DM, DM);
  } else {
    // fallback: round-0 layout + atomic path (no ablation)
    u16* xb    = (u16*)(ws + 0 * MB);
    u16* wqb   = (u16*)(ws + 8 * MB);
    u16* wkb   = (u16*)(ws + 10 * MB);
    u16* wvb   = (u16*)(ws + 12 * MB);
    float* Oacc = (float*)(ws + 0 * MB);
    float* Lacc = (float*)(ws + 16 * MB);
    u16* wob   = (u16*)(ws + 17 * MB);
    u16* Qb    = (u16*)(ws + 19 * MB);
    u16* Kb    = (u16*)(ws + 27 * MB);
    u16* Vtb   = (u16*)(ws + 35 * MB);
    u16* Ctx   = (u16*)(ws + 43 * MB);

    cvt_all<<<8192, 256, 0, stream>>>(x, Wq, Wk, Wv, Wo, xb, wqb, wkb, wvb, wob);
    qkv_gemm<<<dim3(24, 32), 256, 0, stream>>>(xb, wqb, wkb, wvb, Qb, Kb, Vtb);
    zero_kernel<<<4160, 256, 0, stream>>>((float4*)Oacc);
    attn_kernel<0, 0><<<512, 512, 0, stream>>>(Qb, Kb, Vtb, Oacc, Lacc);
    combine_kernel<<<4096, 256, 0, stream>>>(Oacc, Lacc, Ctx);
    o_gemm<<<dim3(8, 64), 256, 0, stream>>>(Ctx, wob, out, S_LEN, DM, DM);
  }
}

// Round 11
// 199.254 us; speedup vs baseline: 1.2545x; 1.2545x over previous
//
#include <hip/hip_runtime.h>
#include <hip/hip_bf16.h>

typedef __attribute__((ext_vector_type(8))) short bf16x8;
typedef __attribute__((ext_vector_type(4))) float f32x4;
typedef unsigned short u16;

#define S_LEN 4096
#define DM 1024
#define NH 16
#define DH 64

// manual RNE fp32->bf16 (inputs never NaN here): 3 VALU ops
__device__ __forceinline__ u16 f2b_rne(float f) {
  unsigned u = __builtin_bit_cast(unsigned, f);
  return (u16)((u + 0x7fffu + ((u >> 16) & 1u)) >> 16);
}
// pack two fp32 -> bf16x2 in one u32 (RNE)
__device__ __forceinline__ unsigned pk2(float a, float b) {
  unsigned ua = __builtin_bit_cast(unsigned, a);
  unsigned ub = __builtin_bit_cast(unsigned, b);
  ua = (ua + 0x7fffu + ((ua >> 16) & 1u)) >> 16;
  ub = (ub + 0x7fffu + ((ub >> 16) & 1u)) & 0xffff0000u;
  return ua | ub;
}
// pack two fp32 -> bf16x2, TRUNCATED: single v_perm_b32 (low=a, high=b).
// bias cancels in softmax (same P in numerator and denominator).
__device__ __forceinline__ unsigned pk2t(float a, float b) {
  return __builtin_amdgcn_perm(__builtin_bit_cast(unsigned, b),
                               __builtin_bit_cast(unsigned, a), 0x07060302u);
}

// global -> LDS direct (16B per lane; lds base must be wave-uniform)
__device__ __forceinline__ void glds16(const u16* g, u16* l) {
  __builtin_amdgcn_global_load_lds(
      (const __attribute__((address_space(1))) unsigned int*)g,
      (__attribute__((address_space(3))) unsigned int*)l, 16, 0, 0);
}

// ---------------- fp32 -> bf16, all 5 inputs in one launch ----------------
__global__ __launch_bounds__(256) void cvt_all(const float* __restrict__ x,
                                               const float* __restrict__ Wq,
                                               const float* __restrict__ Wk,
                                               const float* __restrict__ Wv,
                                               const float* __restrict__ Wo,
                                               u16* __restrict__ xb, u16* __restrict__ wqb,
                                               u16* __restrict__ wkb, u16* __restrict__ wvb,
                                               u16* __restrict__ wob) {
  int idx = (blockIdx.x * 256 + threadIdx.x) * 4;
  const float* src;
  u16* dst;
  int o;
  if (idx < 4194304) {
    src = x; dst = xb; o = idx;
  } else {
    int t = idx - 4194304;
    int wsel = t >> 20;
    o = t & 1048575;
    src = (wsel == 0) ? Wq : (wsel == 1) ? Wk : (wsel == 2) ? Wv : Wo;
    dst = (wsel == 0) ? wqb : (wsel == 1) ? wkb : (wsel == 2) ? wvb : wob;
  }
  float4 v = *(const float4*)(src + o);
  uint2 ov;
  ov.x = pk2(v.x, v.y);
  ov.y = pk2(v.z, v.w);
  *(uint2*)(dst + o) = ov;
}

// ---------------- zero the O/L accumulators (fallback path only) -----------
__global__ __launch_bounds__(256) void zero_kernel(float4* __restrict__ p) {
  p[blockIdx.x * 256 + threadIdx.x] = float4{0.f, 0.f, 0.f, 0.f};
}

// ---------------- fused QKV NT-GEMM with RoPE epilogue; V written transposed
// grid (24, 32): mat = bx>>3 (0=Q rope+scale, 1=K rope, 2=V -> Vt), nb = (bx&7)*128
__global__ __launch_bounds__(256) void qkv_gemm(const u16* __restrict__ A,
                                                const u16* __restrict__ Wq,
                                                const u16* __restrict__ Wk,
                                                const u16* __restrict__ Wv,
                                                u16* __restrict__ Qo, u16* __restrict__ Ko,
                                                u16* __restrict__ Vt) {
  __shared__ __align__(16) u16 As[2 * 128 * 32];
  __shared__ __align__(16) u16 Bs[2 * 128 * 32];
  const int mat = blockIdx.x >> 3;
  const u16* B = (mat == 0) ? Wq : (mat == 1) ? Wk : Wv;
  const int K = DM, N = DM;
  const int tid = threadIdx.x;
  const int wave = tid >> 6, lane = tid & 63;
  const int fm = lane & 15, fq = lane >> 4;
  const int mb = blockIdx.y * 128, nb = (blockIdx.x & 7) * 128;
  const int wm = (wave & 1) * 64, wn = (wave >> 1) * 64;

  f32x4 acc[4][4];
#pragma unroll
  for (int i = 0; i < 4; ++i)
#pragma unroll
    for (int j = 0; j < 4; ++j)
#pragma unroll
      for (int r = 0; r < 4; ++r) acc[i][j][r] = 0.f;

  const int r_ = tid >> 2;
  const int cg = (tid & 3) ^ ((r_ >> 1) & 3);
  const u16* Ag0 = A + (size_t)(mb + r_) * K + cg * 8;
  const u16* Ag1 = A + (size_t)(mb + r_ + 64) * K + cg * 8;
  const u16* Bg0 = B + (size_t)(nb + r_) * K + cg * 8;
  const u16* Bg1 = B + (size_t)(nb + r_ + 64) * K + cg * 8;
  const int l0 = wave * 512;
  const int l1 = 2048 + wave * 512;
  const int sw = (fm >> 1) & 3;

  int buf = 0;
  glds16(Ag0, As + l0);
  glds16(Ag1, As + l1);
  glds16(Bg0, Bs + l0);
  glds16(Bg1, Bs + l1);

  for (int k0 = 0; k0 < K; k0 += 32) {
    __syncthreads();
    if (k0 + 32 < K) {
      int bo = (buf ^ 1) * 4096;
      glds16(Ag0 + k0 + 32, As + bo + l0);
      glds16(Ag1 + k0 + 32, As + bo + l1);
      glds16(Bg0 + k0 + 32, Bs + bo + l0);
      glds16(Bg1 + k0 + 32, Bs + bo + l1);
    }
    const u16* Ab = As + buf * 4096;
    const u16* Bb = Bs + buf * 4096;
    bf16x8 av[4], bv[4];
#pragma unroll
    for (int t = 0; t < 4; ++t) {
      av[t] = *(const bf16x8*)(Ab + (wm + t * 16 + fm) * 32 + ((fq ^ sw) * 8));
      bv[t] = *(const bf16x8*)(Bb + (wn + t * 16 + fm) * 32 + ((fq ^ sw) * 8));
    }
#pragma unroll
    for (int i = 0; i < 4; ++i)
#pragma unroll
      for (int j = 0; j < 4; ++j)
        acc[i][j] = __builtin_amdgcn_mfma_f32_16x16x32_bf16(av[i], bv[j], acc[i][j], 0, 0, 0);
    buf ^= 1;
  }

  if (mat < 2) {
    // RoPE epilogue (in-register): pairs (d, d+32) = regs (j, j+2), d = j*16+fm, j in {0,1}
    u16* Out = (mat == 0) ? Qo : Ko;
    const float qs = (mat == 0) ? 0.1803368801111204f : 1.0f;  // 0.125*log2(e) for Q
    const float c1 = -9.2103403719761836f / 32.f;              // -ln(10000)/32
    const float if0 = __expf((float)fm * c1);
    const float if1 = __expf((float)(16 + fm) * c1);
#pragma unroll
    for (int ii = 0; ii < 4; ++ii) {
#pragma unroll
      for (int r = 0; r < 4; ++r) {
        float s = (float)(mb + wm + ii * 16 + fq * 4 + r);
#pragma unroll
        for (int jp = 0; jp < 2; ++jp) {
          float ang = s * (jp ? if1 : if0);
          float sn, cs;
          __sincosf(ang, &sn, &cs);
          float a = acc[ii][jp][r], b = acc[ii][jp + 2][r];
          acc[ii][jp][r] = (a * cs - b * sn) * qs;
          acc[ii][jp + 2][r] = (b * cs + a * sn) * qs;
        }
      }
    }
#pragma unroll
    for (int i = 0; i < 4; ++i)
#pragma unroll
      for (int j = 0; j < 4; ++j)
#pragma unroll
        for (int r = 0; r < 4; ++r) {
          int row = mb + wm + i * 16 + fq * 4 + r;
          int col = nb + wn + j * 16 + fm;
          Out[(size_t)row * N + col] = f2b_rne(acc[i][j][r]);
        }
  } else {
    // V: write transposed Vt[col][row]; 4 r-values are contiguous rows -> 8B store
#pragma unroll
    for (int i = 0; i < 4; ++i)
#pragma unroll
      for (int j = 0; j < 4; ++j) {
        int col = nb + wn + j * 16 + fm;
        int row0 = mb + wm + i * 16 + fq * 4;
        uint2 pv;
        pv.x = pk2(acc[i][j][0], acc[i][j][1]);
        pv.y = pk2(acc[i][j][2], acc[i][j][3]);
        *(uint2*)(Vt + (size_t)col * S_LEN + row0) = pv;
      }
  }
}

// ---------------- O-projection NT GEMM, 64x128 tiles (fp32 out) -------------
// grid (8, 64): nb = bx*128, mb = by*64. 512 blocks -> real occupancy (vs 256).
__global__ __launch_bounds__(256) void o_gemm(const u16* __restrict__ A,
                                              const u16* __restrict__ B,
                                              float* __restrict__ C, int M, int N, int K) {
  __shared__ __align__(16) u16 As[2 * 64 * 32];
  __shared__ __align__(16) u16 Bs[2 * 128 * 32];
  const int tid = threadIdx.x;
  const int wave = tid >> 6, lane = tid & 63;
  const int fm = lane & 15, fq = lane >> 4;
  const int mb = blockIdx.y * 64, nb = blockIdx.x * 128;
  const int wm = (wave & 1) * 32, wn = (wave >> 1) * 64;

  f32x4 acc[2][4];
#pragma unroll
  for (int i = 0; i < 2; ++i)
#pragma unroll
    for (int j = 0; j < 4; ++j)
#pragma unroll
      for (int r = 0; r < 4; ++r) acc[i][j][r] = 0.f;

  const int r_ = tid >> 2;
  const int cg = (tid & 3) ^ ((r_ >> 1) & 3);
  const u16* Ag0 = A + (size_t)(mb + r_) * K + cg * 8;
  const u16* Bg0 = B + (size_t)(nb + r_) * K + cg * 8;
  const u16* Bg1 = B + (size_t)(nb + r_ + 64) * K + cg * 8;
  const int l0 = wave * 512;
  const int l1 = 2048 + wave * 512;
  const int sw = (fm >> 1) & 3;

  int buf = 0;
  glds16(Ag0, As + l0);
  glds16(Bg0, Bs + l0);
  glds16(Bg1, Bs + l1);

  for (int k0 = 0; k0 < K; k0 += 32) {
    __syncthreads();
    if (k0 + 32 < K) {
      int aoff = (buf ^ 1) * 2048, boff = (buf ^ 1) * 4096;
      glds16(Ag0 + k0 + 32, As + aoff + l0);
      glds16(Bg0 + k0 + 32, Bs + boff + l0);
      glds16(Bg1 + k0 + 32, Bs + boff + l1);
    }
    const u16* Ab = As + buf * 2048;
    const u16* Bb = Bs + buf * 4096;
    bf16x8 av[2], bv[4];
#pragma unroll
    for (int t = 0; t < 2; ++t)
      av[t] = *(const bf16x8*)(Ab + (wm + t * 16 + fm) * 32 + ((fq ^ sw) * 8));
#pragma unroll
    for (int t = 0; t < 4; ++t)
      bv[t] = *(const bf16x8*)(Bb + (wn + t * 16 + fm) * 32 + ((fq ^ sw) * 8));
#pragma unroll
    for (int i = 0; i < 2; ++i)
#pragma unroll
      for (int j = 0; j < 4; ++j)
        acc[i][j] = __builtin_amdgcn_mfma_f32_16x16x32_bf16(av[i], bv[j], acc[i][j], 0, 0, 0);
    buf ^= 1;
  }
#pragma unroll
  for (int i = 0; i < 2; ++i)
#pragma unroll
    for (int j = 0; j < 4; ++j)
#pragma unroll
      for (int r = 0; r < 4; ++r) {
        int row = mb + wm + i * 16 + fq * 4 + r;
        int col = nb + wn + j * 16 + fm;
        C[(size_t)row * N + col] = acc[i][j][r];
      }
}

// ---------------- causal flash attention v16: register-only softmax --------
// Ablation (r10) proved the back-end Ps LDS round-trip is the wall (~48 of
// 78.6 us; front-end floor = 30 us). v16 removes it with ZERO cross-lane:
// K rows are staged PERMUTED (bit-permutation g(s): source address of
// glds16 is per-lane free), so QK^T's output st[g][t][r] =
// P^T[k = fq*8 + (t&1)*4 + r][q = fm] is EXACTLY the 16x16x32 MFMA
// B-operand layout. PV becomes o^T[d][q] = mfma(A=V-frag, B=pack(st)) —
// P never leaves registers. V fragments and lsum-vone MFMAs unchanged in
// shape/count. Causal mask uses the permuted key index. Epilogue: D is
// [d][q] -> per-lane float4 stores. LDS 51,200 -> 32,768 B.
template <int STORE>
__global__ __launch_bounds__(512, 4) void attn_kernel(const u16* __restrict__ Q,
                                                      const u16* __restrict__ K,
                                                      const u16* __restrict__ Vt,
                                                      float* __restrict__ Oacc,
                                                      float* __restrict__ Lacc) {
  __shared__ __align__(16) u16 Ks[2 * 4096];   // 2 x (64 key x 64 d), swizzled, rows permuted
  __shared__ __align__(16) u16 Vs[2 * 4096];   // 2 x (64 d x 64 key), swizzled
  const int tid = threadIdx.x;
  const int w = tid >> 6, lane = tid & 63;
  const int fm = lane & 15, fq = lane >> 4;
  const int bid = blockIdx.x;       // [0,512)
  const int u = bid & 255, hi = bid >> 8;
  const int h = u & 15;
  const int qt0 = u >> 4;           // [0,16)
  const int qt = hi ? qt0 : 15 - qt0;
  const int half = hi;
  const int qb = qt * 256 + w * 32;
  const int nlocal = 2 * qt + 2;    // tiles per half (total 4qt+4)
  const int kbase = half * nlocal;
  const int dtile = qb >> 6;        // == dtile: partial mask; > dtile: skip

  bf16x8 q0[2], q1[2];
#pragma unroll
  for (int g = 0; g < 2; ++g) {
    const u16* qp = Q + (size_t)(qb + g * 16 + fm) * DM + h * DH + fq * 8;
    q0[g] = *(const bf16x8*)(qp);
    q1[g] = *(const bf16x8*)(qp + 32);
  }
  f32x4 o[2][4];
  f32x4 ls[2];
#pragma unroll
  for (int g = 0; g < 2; ++g) {
#pragma unroll
    for (int r = 0; r < 4; ++r) ls[g][r] = 0.f;
#pragma unroll
    for (int c4 = 0; c4 < 4; ++c4)
#pragma unroll
      for (int r = 0; r < 4; ++r) o[g][c4][r] = 0.f;
  }
  const short ONEB = (short)0x3F80;  // 1.0 bf16
  const bf16x8 vone = {ONEB, ONEB, ONEB, ONEB, ONEB, ONEB, ONEB, ONEB};

  // staging: 512 slots x 16B = one full 64x64 tile; slot = tid.
  // row = tid>>3, stored chunk = tid&7, global chunk = (tid&7) ^ (row&7).
  // K rows permuted: LDS row s holds global key g(s), the 6-bit permutation
  // [b5 b4 b3 b2 b1 b0] -> key bits [b5 | b3 b2 | b4 | b1 b0], which makes
  // st's (t,fq,r) layout coincide with the MFMA B-operand k = fq*8+(t&1)*4+r.
  const int rr = tid >> 3;                 // [0,64)  (LDS row)
  const int cc8 = (tid & 7) ^ (rr & 7);
  const int grr = ((rr >> 5) << 5) | (((rr >> 2) & 3) << 3) | (((rr >> 4) & 1) << 2) | (rr & 3);
  const u16* Kg = K + (size_t)grr * DM + h * DH + cc8 * 8;
  const u16* Vg = Vt + (size_t)(h * DH + rr) * S_LEN + cc8 * 8;
  const int l0 = w * 512;                  // wave-uniform LDS base (u16)
  const int sw7 = fm & 7;
  const f32x4 zf = {0.f, 0.f, 0.f, 0.f};

  glds16(Kg + (size_t)kbase * 64 * DM, Ks + l0);
  glds16(Vg + kbase * 64, Vs + l0);

  int buf = 0;
  for (int kl = 0; kl < nlocal; ++kl) {
    const int ktg = kbase + kl;
    __syncthreads();
    if (kl + 1 < nlocal) {
      int bo = (buf ^ 1) * 4096;
      glds16(Kg + (size_t)(ktg + 1) * 64 * DM, Ks + bo + l0);
      glds16(Vg + (ktg + 1) * 64, Vs + bo + l0);
    }
    if (ktg <= dtile) {
      const u16* Kb = Ks + buf * 4096;
      const u16* Vb = Vs + buf * 4096;

      // S^T = K * Q^T over permuted-staged K rows: st[g][t][r] holds
      // P-logits for key = ktg*64 + (t>>1)*32 + fq*8 + (t&1)*4 + r, q = fm
      f32x4 st[2][4];
#pragma unroll
      for (int t = 0; t < 4; ++t) {
        const u16* kr = Kb + (t * 16 + fm) * 64;
        bf16x8 ka = *(const bf16x8*)(kr + ((fq ^ sw7) * 8));
        bf16x8 kb2 = *(const bf16x8*)(kr + (((fq + 4) ^ sw7) * 8));
#pragma unroll
        for (int g = 0; g < 2; ++g) {
          f32x4 s = __builtin_amdgcn_mfma_f32_16x16x32_bf16(ka, q0[g], zf, 0, 0, 0);
          st[g][t] = __builtin_amdgcn_mfma_f32_16x16x32_bf16(kb2, q1[g], s, 0, 0, 0);
        }
      }
      if (ktg == dtile) {  // diagonal tile: partial causal mask (permuted keys)
#pragma unroll
        for (int g = 0; g < 2; ++g) {
          int qg = qb + g * 16 + fm;
#pragma unroll
          for (int t = 0; t < 4; ++t) {
            int key = ktg * 64 + (t >> 1) * 32 + fq * 8 + (t & 1) * 4;
#pragma unroll
            for (int r = 0; r < 4; ++r)
              st[g][t][r] = (key + r > qg) ? -1e30f : st[g][t][r];
          }
        }
      }
      // V A-operand fragments (unchanged addressing; shared across g)
      bf16x8 pvb[4][2];
#pragma unroll
      for (int c4 = 0; c4 < 4; ++c4) {
        const u16* vr = Vb + (c4 * 16 + fm) * 64;
        pvb[c4][0] = *(const bf16x8*)(vr + ((fq ^ sw7) * 8));
        pvb[c4][1] = *(const bf16x8*)(vr + (((fq + 4) ^ sw7) * 8));
      }
      // register-only softmax+PV: exp2 -> pack -> MFMA (no LDS, no drains)
#pragma unroll
      for (int g = 0; g < 2; ++g) {
        unsigned pw[8];
#pragma unroll
        for (int t = 0; t < 4; ++t) {
          float p0 = __builtin_amdgcn_exp2f(st[g][t][0]);
          float p1 = __builtin_amdgcn_exp2f(st[g][t][1]);
          float p2 = __builtin_amdgcn_exp2f(st[g][t][2]);
          float p3 = __builtin_amdgcn_exp2f(st[g][t][3]);
          pw[t * 2] = pk2t(p0, p1);
          pw[t * 2 + 1] = pk2t(p2, p3);
        }
        uint4 u0 = {pw[0], pw[1], pw[2], pw[3]};
        uint4 u1 = {pw[4], pw[5], pw[6], pw[7]};
        bf16x8 pb0 = __builtin_bit_cast(bf16x8, u0);  // B-frag, keys 0..31 of tile
        bf16x8 pb1 = __builtin_bit_cast(bf16x8, u1);  // B-frag, keys 32..63
        ls[g] = __builtin_amdgcn_mfma_f32_16x16x32_bf16(vone, pb0, ls[g], 0, 0, 0);
        ls[g] = __builtin_amdgcn_mfma_f32_16x16x32_bf16(vone, pb1, ls[g], 0, 0, 0);
#pragma unroll
        for (int c4 = 0; c4 < 4; ++c4) {
          o[g][c4] = __builtin_amdgcn_mfma_f32_16x16x32_bf16(pvb[c4][0], pb0, o[g][c4], 0, 0, 0);
          o[g][c4] = __builtin_amdgcn_mfma_f32_16x16x32_bf16(pvb[c4][1], pb1, o[g][c4], 0, 0, 0);
        }
      }
    }
    buf ^= 1;
  }
  // D layout now [d][q]: lane (fm,fq) reg r holds o for q = g*16+fm,
  // d = c4*16 + fq*4 + r. ls[g][*] all hold l[q = g*16+fm].
  if (STORE) {
    float* Ob = Oacc + (((size_t)half * NH + h) * S_LEN + qt * 256 + w * 32) * DH;
    float* Lb = Lacc + ((size_t)half * NH + h) * S_LEN + qt * 256 + w * 32;
#pragma unroll
    for (int g = 0; g < 2; ++g) {
      if (fq == 0) Lb[g * 16 + fm] = ls[g][0];
#pragma unroll
      for (int c4 = 0; c4 < 4; ++c4)
        *(float4*)(Ob + (size_t)(g * 16 + fm) * DH + c4 * 16 + fq * 4) =
            float4{o[g][c4][0], o[g][c4][1], o[g][c4][2], o[g][c4][3]};
    }
  } else {
    // fallback: atomic accumulate into shared Oacc/Lacc
    float* Ob = Oacc + ((size_t)h * S_LEN + qt * 256 + w * 32) * DH;
    float* Lb = Lacc + h * S_LEN + qt * 256 + w * 32;
#pragma unroll
    for (int g = 0; g < 2; ++g) {
      if (fq == 0) unsafeAtomicAdd(Lb + g * 16 + fm, ls[g][0]);
#pragma unroll
      for (int c4 = 0; c4 < 4; ++c4)
#pragma unroll
        for (int r = 0; r < 4; ++r)
          unsafeAtomicAdd(Ob + (size_t)(g * 16 + fm) * DH + c4 * 16 + fq * 4 + r, o[g][c4][r]);
    }
  }
}

// ---------------- combine (store path): Ctx = bf16((O0+O1) / (L0+L1)) ------
__global__ __launch_bounds__(256) void combine2_kernel(const float* __restrict__ O0,
                                                       const float* __restrict__ O1,
                                                       const float* __restrict__ L0,
                                                       const float* __restrict__ L1,
                                                       u16* __restrict__ Ctx) {
  int idx = blockIdx.x * 256 + threadIdx.x;  // 1,048,576 threads
  int d4 = (idx & 15) * 4;
  int hh = (idx >> 4) & 15;
  int row = idx >> 8;
  size_t ob = ((size_t)hh * S_LEN + row) * DH + d4;
  float4 a = *(const float4*)(O0 + ob);
  float4 b = *(const float4*)(O1 + ob);
  float il = 1.0f / (L0[hh * S_LEN + row] + L1[hh * S_LEN + row]);
  uint2 o;
  o.x = pk2((a.x + b.x) * il, (a.y + b.y) * il);
  o.y = pk2((a.z + b.z) * il, (a.w + b.w) * il);
  *(uint2*)(Ctx + (size_t)row * DM + hh * DH + d4) = o;
}

// ---------------- combine (atomic fallback): Ctx = bf16(Oacc / Lacc) --------
__global__ __launch_bounds__(256) void combine_kernel(const float* __restrict__ Oacc,
                                                      const float* __restrict__ Lacc,
                                                      u16* __restrict__ Ctx) {
  int idx = blockIdx.x * 256 + threadIdx.x;  // 1,048,576 threads
  int d4 = (idx & 15) * 4;
  int hh = (idx >> 4) & 15;
  int row = idx >> 8;
  float4 a = *(const float4*)(Oacc + ((size_t)hh * S_LEN + row) * DH + d4);
  float il = 1.0f / Lacc[hh * S_LEN + row];
  uint2 o;
  o.x = pk2(a.x * il, a.y * il);
  o.y = pk2(a.z * il, a.w * il);
  *(uint2*)(Ctx + (size_t)row * DM + hh * DH + d4) = o;
}

extern "C" void kernel_launch(void* const* d_in, const int* in_sizes, int n_in,
                              void* d_out, int out_size, void* d_ws, size_t ws_size,
                              hipStream_t stream) {
  const float* x  = (const float*)d_in[0];
  const float* Wq = (const float*)d_in[1];
  const float* Wk = (const float*)d_in[2];
  const float* Wv = (const float*)d_in[3];
  const float* Wo = (const float*)d_in[4];
  float* out = (float*)d_out;

  const size_t MB = 1u << 20;
  char* ws = (char*)d_ws;

  if (ws_size >= 72 * MB) {
    // store-path layout (72 MB):
    //  [0,8)   xb         -> Ctx (after attn)
    //  [8,14)  wqb/wkb/wvb -> Lpart [8,8.5) (after qkv)
    //  [14,16) wob (persists to o_gemm)
    //  [16,40) Qb, Kb, Vtb
    //  [40,72) Opart [2][16][4096][64] fp32
    u16* xb    = (u16*)(ws + 0 * MB);
    u16* wqb   = (u16*)(ws + 8 * MB);
    u16* wkb   = (u16*)(ws + 10 * MB);
    u16* wvb   = (u16*)(ws + 12 * MB);
    u16* wob   = (u16*)(ws + 14 * MB);
    u16* Qb    = (u16*)(ws + 16 * MB);
    u16* Kb    = (u16*)(ws + 24 * MB);
    u16* Vtb   = (u16*)(ws + 32 * MB);
    float* Op  = (float*)(ws + 40 * MB);
    float* Lp  = (float*)(ws + 8 * MB);
    u16* Ctx   = (u16*)(ws + 0 * MB);

    cvt_all<<<8192, 256, 0, stream>>>(x, Wq, Wk, Wv, Wo, xb, wqb, wkb, wvb, wob);
    qkv_gemm<<<dim3(24, 32), 256, 0, stream>>>(xb, wqb, wkb, wvb, Qb, Kb, Vtb);
    attn_kernel<1><<<512, 512, 0, stream>>>(Qb, Kb, Vtb, Op, Lp);
    combine2_kernel<<<4096, 256, 0, stream>>>(Op, Op + (size_t)NH * S_LEN * DH,
                                              Lp, Lp + (size_t)NH * S_LEN, Ctx);
    o_gemm<<<dim3(8, 64), 256, 0, stream>>>(Ctx, wob, out, S_LEN, DM, DM);
  } else {
    // fallback: round-0 layout + atomic path
    u16* xb    = (u16*)(ws + 0 * MB);
    u16* wqb   = (u16*)(ws + 8 * MB);
    u16* wkb   = (u16*)(ws + 10 * MB);
    u16* wvb   = (u16*)(ws + 12 * MB);
    float* Oacc = (float*)(ws + 0 * MB);
    float* Lacc = (float*)(ws + 16 * MB);
    u16* wob   = (u16*)(ws + 17 * MB);
    u16* Qb    = (u16*)(ws + 19 * MB);
    u16* Kb    = (u16*)(ws + 27 * MB);
    u16* Vtb   = (u16*)(ws + 35 * MB);
    u16* Ctx   = (u16*)(ws + 43 * MB);

    cvt_all<<<8192, 256, 0, stream>>>(x, Wq, Wk, Wv, Wo, xb, wqb, wkb, wvb, wob);
    qkv_gemm<<<dim3(24, 32), 256, 0, stream>>>(xb, wqb, wkb, wvb, Qb, Kb, Vtb);
    zero_kernel<<<4160, 256, 0, stream>>>((float4*)Oacc);
    attn_kernel<0><<<512, 512, 0, stream>>>(Qb, Kb, Vtb, Oacc, Lacc);
    combine_kernel<<<4096, 256, 0, stream>>>(Oacc, Lacc, Ctx);
    o_gemm<<<dim3(8, 64), 256, 0, stream>>>(Ctx, wob, out, S_LEN, DM, DM);
  }
}

// Round 12
// 198.171 us; speedup vs baseline: 1.2614x; 1.0055x over previous
//
#include <hip/hip_runtime.h>
#include <hip/hip_bf16.h>

typedef __attribute__((ext_vector_type(8))) short bf16x8;
typedef __attribute__((ext_vector_type(4))) float f32x4;
typedef unsigned short u16;

#define S_LEN 4096
#define DM 1024
#define NH 16
#define DH 64

// manual RNE fp32->bf16 (inputs never NaN here): 3 VALU ops
__device__ __forceinline__ u16 f2b_rne(float f) {
  unsigned u = __builtin_bit_cast(unsigned, f);
  return (u16)((u + 0x7fffu + ((u >> 16) & 1u)) >> 16);
}
// pack two fp32 -> bf16x2 in one u32 (RNE)
__device__ __forceinline__ unsigned pk2(float a, float b) {
  unsigned ua = __builtin_bit_cast(unsigned, a);
  unsigned ub = __builtin_bit_cast(unsigned, b);
  ua = (ua + 0x7fffu + ((ua >> 16) & 1u)) >> 16;
  ub = (ub + 0x7fffu + ((ub >> 16) & 1u)) & 0xffff0000u;
  return ua | ub;
}
// pack two fp32 -> bf16x2, TRUNCATED: single v_perm_b32 (low=a, high=b).
// bias cancels in softmax (same P in numerator and denominator).
__device__ __forceinline__ unsigned pk2t(float a, float b) {
  return __builtin_amdgcn_perm(__builtin_bit_cast(unsigned, b),
                               __builtin_bit_cast(unsigned, a), 0x07060302u);
}

// global -> LDS direct (16B per lane; lds base must be wave-uniform)
__device__ __forceinline__ void glds16(const u16* g, u16* l) {
  __builtin_amdgcn_global_load_lds(
      (const __attribute__((address_space(1))) unsigned int*)g,
      (__attribute__((address_space(3))) unsigned int*)l, 16, 0, 0);
}

// ---------------- fp32 -> bf16, all 5 inputs in one launch ----------------
__global__ __launch_bounds__(256) void cvt_all(const float* __restrict__ x,
                                               const float* __restrict__ Wq,
                                               const float* __restrict__ Wk,
                                               const float* __restrict__ Wv,
                                               const float* __restrict__ Wo,
                                               u16* __restrict__ xb, u16* __restrict__ wqb,
                                               u16* __restrict__ wkb, u16* __restrict__ wvb,
                                               u16* __restrict__ wob) {
  int idx = (blockIdx.x * 256 + threadIdx.x) * 4;
  const float* src;
  u16* dst;
  int o;
  if (idx < 4194304) {
    src = x; dst = xb; o = idx;
  } else {
    int t = idx - 4194304;
    int wsel = t >> 20;
    o = t & 1048575;
    src = (wsel == 0) ? Wq : (wsel == 1) ? Wk : (wsel == 2) ? Wv : Wo;
    dst = (wsel == 0) ? wqb : (wsel == 1) ? wkb : (wsel == 2) ? wvb : wob;
  }
  float4 v = *(const float4*)(src + o);
  uint2 ov;
  ov.x = pk2(v.x, v.y);
  ov.y = pk2(v.z, v.w);
  *(uint2*)(dst + o) = ov;
}

// ---------------- zero the O/L accumulators (fallback path only) -----------
__global__ __launch_bounds__(256) void zero_kernel(float4* __restrict__ p) {
  p[blockIdx.x * 256 + threadIdx.x] = float4{0.f, 0.f, 0.f, 0.f};
}

// ---------------- fused QKV NT-GEMM with RoPE epilogue; V written transposed
// grid (24, 32): mat = bx>>3 (0=Q rope+scale, 1=K rope, 2=V -> Vt), nb = (bx&7)*128
__global__ __launch_bounds__(256) void qkv_gemm(const u16* __restrict__ A,
                                                const u16* __restrict__ Wq,
                                                const u16* __restrict__ Wk,
                                                const u16* __restrict__ Wv,
                                                u16* __restrict__ Qo, u16* __restrict__ Ko,
                                                u16* __restrict__ Vt) {
  __shared__ __align__(16) u16 As[2 * 128 * 32];
  __shared__ __align__(16) u16 Bs[2 * 128 * 32];
  const int mat = blockIdx.x >> 3;
  const u16* B = (mat == 0) ? Wq : (mat == 1) ? Wk : Wv;
  const int K = DM, N = DM;
  const int tid = threadIdx.x;
  const int wave = tid >> 6, lane = tid & 63;
  const int fm = lane & 15, fq = lane >> 4;
  const int mb = blockIdx.y * 128, nb = (blockIdx.x & 7) * 128;
  const int wm = (wave & 1) * 64, wn = (wave >> 1) * 64;

  f32x4 acc[4][4];
#pragma unroll
  for (int i = 0; i < 4; ++i)
#pragma unroll
    for (int j = 0; j < 4; ++j)
#pragma unroll
      for (int r = 0; r < 4; ++r) acc[i][j][r] = 0.f;

  const int r_ = tid >> 2;
  const int cg = (tid & 3) ^ ((r_ >> 1) & 3);
  const u16* Ag0 = A + (size_t)(mb + r_) * K + cg * 8;
  const u16* Ag1 = A + (size_t)(mb + r_ + 64) * K + cg * 8;
  const u16* Bg0 = B + (size_t)(nb + r_) * K + cg * 8;
  const u16* Bg1 = B + (size_t)(nb + r_ + 64) * K + cg * 8;
  const int l0 = wave * 512;
  const int l1 = 2048 + wave * 512;
  const int sw = (fm >> 1) & 3;

  int buf = 0;
  glds16(Ag0, As + l0);
  glds16(Ag1, As + l1);
  glds16(Bg0, Bs + l0);
  glds16(Bg1, Bs + l1);

  for (int k0 = 0; k0 < K; k0 += 32) {
    __syncthreads();
    if (k0 + 32 < K) {
      int bo = (buf ^ 1) * 4096;
      glds16(Ag0 + k0 + 32, As + bo + l0);
      glds16(Ag1 + k0 + 32, As + bo + l1);
      glds16(Bg0 + k0 + 32, Bs + bo + l0);
      glds16(Bg1 + k0 + 32, Bs + bo + l1);
    }
    const u16* Ab = As + buf * 4096;
    const u16* Bb = Bs + buf * 4096;
    bf16x8 av[4], bv[4];
#pragma unroll
    for (int t = 0; t < 4; ++t) {
      av[t] = *(const bf16x8*)(Ab + (wm + t * 16 + fm) * 32 + ((fq ^ sw) * 8));
      bv[t] = *(const bf16x8*)(Bb + (wn + t * 16 + fm) * 32 + ((fq ^ sw) * 8));
    }
#pragma unroll
    for (int i = 0; i < 4; ++i)
#pragma unroll
      for (int j = 0; j < 4; ++j)
        acc[i][j] = __builtin_amdgcn_mfma_f32_16x16x32_bf16(av[i], bv[j], acc[i][j], 0, 0, 0);
    buf ^= 1;
  }

  if (mat < 2) {
    // RoPE epilogue (in-register): pairs (d, d+32) = regs (j, j+2), d = j*16+fm, j in {0,1}
    u16* Out = (mat == 0) ? Qo : Ko;
    const float qs = (mat == 0) ? 0.1803368801111204f : 1.0f;  // 0.125*log2(e) for Q
    const float c1 = -9.2103403719761836f / 32.f;              // -ln(10000)/32
    const float if0 = __expf((float)fm * c1);
    const float if1 = __expf((float)(16 + fm) * c1);
#pragma unroll
    for (int ii = 0; ii < 4; ++ii) {
#pragma unroll
      for (int r = 0; r < 4; ++r) {
        float s = (float)(mb + wm + ii * 16 + fq * 4 + r);
#pragma unroll
        for (int jp = 0; jp < 2; ++jp) {
          float ang = s * (jp ? if1 : if0);
          float sn, cs;
          __sincosf(ang, &sn, &cs);
          float a = acc[ii][jp][r], b = acc[ii][jp + 2][r];
          acc[ii][jp][r] = (a * cs - b * sn) * qs;
          acc[ii][jp + 2][r] = (b * cs + a * sn) * qs;
        }
      }
    }
#pragma unroll
    for (int i = 0; i < 4; ++i)
#pragma unroll
      for (int j = 0; j < 4; ++j)
#pragma unroll
        for (int r = 0; r < 4; ++r) {
          int row = mb + wm + i * 16 + fq * 4 + r;
          int col = nb + wn + j * 16 + fm;
          Out[(size_t)row * N + col] = f2b_rne(acc[i][j][r]);
        }
  } else {
    // V: write transposed Vt[col][row]; 4 r-values are contiguous rows -> 8B store
#pragma unroll
    for (int i = 0; i < 4; ++i)
#pragma unroll
      for (int j = 0; j < 4; ++j) {
        int col = nb + wn + j * 16 + fm;
        int row0 = mb + wm + i * 16 + fq * 4;
        uint2 pv;
        pv.x = pk2(acc[i][j][0], acc[i][j][1]);
        pv.y = pk2(acc[i][j][2], acc[i][j][3]);
        *(uint2*)(Vt + (size_t)col * S_LEN + row0) = pv;
      }
  }
}

// ---------------- O-projection NT GEMM, 64x128 tiles (fp32 out) -------------
// grid (8, 64): nb = bx*128, mb = by*64. 512 blocks -> real occupancy (vs 256).
__global__ __launch_bounds__(256) void o_gemm(const u16* __restrict__ A,
                                              const u16* __restrict__ B,
                                              float* __restrict__ C, int M, int N, int K) {
  __shared__ __align__(16) u16 As[2 * 64 * 32];
  __shared__ __align__(16) u16 Bs[2 * 128 * 32];
  const int tid = threadIdx.x;
  const int wave = tid >> 6, lane = tid & 63;
  const int fm = lane & 15, fq = lane >> 4;
  const int mb = blockIdx.y * 64, nb = blockIdx.x * 128;
  const int wm = (wave & 1) * 32, wn = (wave >> 1) * 64;

  f32x4 acc[2][4];
#pragma unroll
  for (int i = 0; i < 2; ++i)
#pragma unroll
    for (int j = 0; j < 4; ++j)
#pragma unroll
      for (int r = 0; r < 4; ++r) acc[i][j][r] = 0.f;

  const int r_ = tid >> 2;
  const int cg = (tid & 3) ^ ((r_ >> 1) & 3);
  const u16* Ag0 = A + (size_t)(mb + r_) * K + cg * 8;
  const u16* Bg0 = B + (size_t)(nb + r_) * K + cg * 8;
  const u16* Bg1 = B + (size_t)(nb + r_ + 64) * K + cg * 8;
  const int l0 = wave * 512;
  const int l1 = 2048 + wave * 512;
  const int sw = (fm >> 1) & 3;

  int buf = 0;
  glds16(Ag0, As + l0);
  glds16(Bg0, Bs + l0);
  glds16(Bg1, Bs + l1);

  for (int k0 = 0; k0 < K; k0 += 32) {
    __syncthreads();
    if (k0 + 32 < K) {
      int aoff = (buf ^ 1) * 2048, boff = (buf ^ 1) * 4096;
      glds16(Ag0 + k0 + 32, As + aoff + l0);
      glds16(Bg0 + k0 + 32, Bs + boff + l0);
      glds16(Bg1 + k0 + 32, Bs + boff + l1);
    }
    const u16* Ab = As + buf * 2048;
    const u16* Bb = Bs + buf * 4096;
    bf16x8 av[2], bv[4];
#pragma unroll
    for (int t = 0; t < 2; ++t)
      av[t] = *(const bf16x8*)(Ab + (wm + t * 16 + fm) * 32 + ((fq ^ sw) * 8));
#pragma unroll
    for (int t = 0; t < 4; ++t)
      bv[t] = *(const bf16x8*)(Bb + (wn + t * 16 + fm) * 32 + ((fq ^ sw) * 8));
#pragma unroll
    for (int i = 0; i < 2; ++i)
#pragma unroll
      for (int j = 0; j < 4; ++j)
        acc[i][j] = __builtin_amdgcn_mfma_f32_16x16x32_bf16(av[i], bv[j], acc[i][j], 0, 0, 0);
    buf ^= 1;
  }
#pragma unroll
  for (int i = 0; i < 2; ++i)
#pragma unroll
    for (int j = 0; j < 4; ++j)
#pragma unroll
      for (int r = 0; r < 4; ++r) {
        int row = mb + wm + i * 16 + fq * 4 + r;
        int col = nb + wn + j * 16 + fm;
        C[(size_t)row * N + col] = acc[i][j][r];
      }
}

// ---------------- causal flash attention v17: reg-softmax + 4-way split ----
// v16 (register-only softmax via permuted K staging; 52.3 us, 0 bank
// conflicts) + NSPLIT=4 work decomposition: 4qt+4 tiles split into 4 equal
// chunks of qt+1 (max 16 iters vs 32), grid 1024 longest-first, 4 blocks/CU
// (LDS 4x32KB=131KB, 32 waves). Per-CU pipe work unchanged; the serial
// critical chain halves and 4 independent blocks interleave to fill pipes.
// Store path only (Opart[NSPLIT] partials, no atomics).
template <int STORE, int NSPLIT>
__global__ __launch_bounds__(512, 4) void attn_kernel(const u16* __restrict__ Q,
                                                      const u16* __restrict__ K,
                                                      const u16* __restrict__ Vt,
                                                      float* __restrict__ Oacc,
                                                      float* __restrict__ Lacc) {
  __shared__ __align__(16) u16 Ks[2 * 4096];   // 2 x (64 key x 64 d), swizzled, rows permuted
  __shared__ __align__(16) u16 Vs[2 * 4096];   // 2 x (64 d x 64 key), swizzled
  const int tid = threadIdx.x;
  const int w = tid >> 6, lane = tid & 63;
  const int fm = lane & 15, fq = lane >> 4;
  const int bid = blockIdx.x;
  int qt, h, half, kbase, nlocal;
  if (NSPLIT == 4) {
    // bid in [0,1024): [qt-desc:4][chunk:2][h:4]; chunks of qt+1 tiles each
    qt = 15 - (bid >> 6);
    half = (bid >> 4) & 3;
    h = bid & 15;
    nlocal = qt + 1;
    kbase = half * nlocal;
  } else {
    // bid in [0,512): complement-paired halves (v16 mapping)
    const int u = bid & 255, hi = bid >> 8;
    h = u & 15;
    const int qt0 = u >> 4;
    qt = hi ? qt0 : 15 - qt0;
    half = hi;
    nlocal = 2 * qt + 2;
    kbase = half * nlocal;
  }
  const int qb = qt * 256 + w * 32;
  const int dtile = qb >> 6;        // == dtile: partial mask; > dtile: skip

  bf16x8 q0[2], q1[2];
#pragma unroll
  for (int g = 0; g < 2; ++g) {
    const u16* qp = Q + (size_t)(qb + g * 16 + fm) * DM + h * DH + fq * 8;
    q0[g] = *(const bf16x8*)(qp);
    q1[g] = *(const bf16x8*)(qp + 32);
  }
  f32x4 o[2][4];
  f32x4 ls[2];
#pragma unroll
  for (int g = 0; g < 2; ++g) {
#pragma unroll
    for (int r = 0; r < 4; ++r) ls[g][r] = 0.f;
#pragma unroll
    for (int c4 = 0; c4 < 4; ++c4)
#pragma unroll
      for (int r = 0; r < 4; ++r) o[g][c4][r] = 0.f;
  }
  const short ONEB = (short)0x3F80;  // 1.0 bf16
  const bf16x8 vone = {ONEB, ONEB, ONEB, ONEB, ONEB, ONEB, ONEB, ONEB};

  // staging: 512 slots x 16B = one full 64x64 tile; slot = tid.
  // row = tid>>3, stored chunk = tid&7, global chunk = (tid&7) ^ (row&7).
  // K rows permuted: LDS row s holds global key g(s), the 6-bit permutation
  // [b5 b4 b3 b2 b1 b0] -> key bits [b5 | b3 b2 | b4 | b1 b0], which makes
  // st's (t,fq,r) layout coincide with the MFMA B-operand k = fq*8+(t&1)*4+r.
  const int rr = tid >> 3;                 // [0,64)  (LDS row)
  const int cc8 = (tid & 7) ^ (rr & 7);
  const int grr = ((rr >> 5) << 5) | (((rr >> 2) & 3) << 3) | (((rr >> 4) & 1) << 2) | (rr & 3);
  const u16* Kg = K + (size_t)grr * DM + h * DH + cc8 * 8;
  const u16* Vg = Vt + (size_t)(h * DH + rr) * S_LEN + cc8 * 8;
  const int l0 = w * 512;                  // wave-uniform LDS base (u16)
  const int sw7 = fm & 7;
  const f32x4 zf = {0.f, 0.f, 0.f, 0.f};

  glds16(Kg + (size_t)kbase * 64 * DM, Ks + l0);
  glds16(Vg + kbase * 64, Vs + l0);

  int buf = 0;
  for (int kl = 0; kl < nlocal; ++kl) {
    const int ktg = kbase + kl;
    __syncthreads();
    if (kl + 1 < nlocal) {
      int bo = (buf ^ 1) * 4096;
      glds16(Kg + (size_t)(ktg + 1) * 64 * DM, Ks + bo + l0);
      glds16(Vg + (ktg + 1) * 64, Vs + bo + l0);
    }
    if (ktg <= dtile) {
      const u16* Kb = Ks + buf * 4096;
      const u16* Vb = Vs + buf * 4096;

      // S^T = K * Q^T over permuted-staged K rows: st[g][t][r] holds
      // P-logits for key = ktg*64 + (t>>1)*32 + fq*8 + (t&1)*4 + r, q = fm
      f32x4 st[2][4];
#pragma unroll
      for (int t = 0; t < 4; ++t) {
        const u16* kr = Kb + (t * 16 + fm) * 64;
        bf16x8 ka = *(const bf16x8*)(kr + ((fq ^ sw7) * 8));
        bf16x8 kb2 = *(const bf16x8*)(kr + (((fq + 4) ^ sw7) * 8));
#pragma unroll
        for (int g = 0; g < 2; ++g) {
          f32x4 s = __builtin_amdgcn_mfma_f32_16x16x32_bf16(ka, q0[g], zf, 0, 0, 0);
          st[g][t] = __builtin_amdgcn_mfma_f32_16x16x32_bf16(kb2, q1[g], s, 0, 0, 0);
        }
      }
      if (ktg == dtile) {  // diagonal tile: partial causal mask (permuted keys)
#pragma unroll
        for (int g = 0; g < 2; ++g) {
          int qg = qb + g * 16 + fm;
#pragma unroll
          for (int t = 0; t < 4; ++t) {
            int key = ktg * 64 + (t >> 1) * 32 + fq * 8 + (t & 1) * 4;
#pragma unroll
            for (int r = 0; r < 4; ++r)
              st[g][t][r] = (key + r > qg) ? -1e30f : st[g][t][r];
          }
        }
      }
      // V A-operand fragments (unchanged addressing; shared across g)
      bf16x8 pvb[4][2];
#pragma unroll
      for (int c4 = 0; c4 < 4; ++c4) {
        const u16* vr = Vb + (c4 * 16 + fm) * 64;
        pvb[c4][0] = *(const bf16x8*)(vr + ((fq ^ sw7) * 8));
        pvb[c4][1] = *(const bf16x8*)(vr + (((fq + 4) ^ sw7) * 8));
      }
      // register-only softmax+PV: exp2 -> pack -> MFMA (no LDS, no drains)
#pragma unroll
      for (int g = 0; g < 2; ++g) {
        unsigned pw[8];
#pragma unroll
        for (int t = 0; t < 4; ++t) {
          float p0 = __builtin_amdgcn_exp2f(st[g][t][0]);
          float p1 = __builtin_amdgcn_exp2f(st[g][t][1]);
          float p2 = __builtin_amdgcn_exp2f(st[g][t][2]);
          float p3 = __builtin_amdgcn_exp2f(st[g][t][3]);
          pw[t * 2] = pk2t(p0, p1);
          pw[t * 2 + 1] = pk2t(p2, p3);
        }
        uint4 u0 = {pw[0], pw[1], pw[2], pw[3]};
        uint4 u1 = {pw[4], pw[5], pw[6], pw[7]};
        bf16x8 pb0 = __builtin_bit_cast(bf16x8, u0);  // B-frag, keys 0..31 of tile
        bf16x8 pb1 = __builtin_bit_cast(bf16x8, u1);  // B-frag, keys 32..63
        ls[g] = __builtin_amdgcn_mfma_f32_16x16x32_bf16(vone, pb0, ls[g], 0, 0, 0);
        ls[g] = __builtin_amdgcn_mfma_f32_16x16x32_bf16(vone, pb1, ls[g], 0, 0, 0);
#pragma unroll
        for (int c4 = 0; c4 < 4; ++c4) {
          o[g][c4] = __builtin_amdgcn_mfma_f32_16x16x32_bf16(pvb[c4][0], pb0, o[g][c4], 0, 0, 0);
          o[g][c4] = __builtin_amdgcn_mfma_f32_16x16x32_bf16(pvb[c4][1], pb1, o[g][c4], 0, 0, 0);
        }
      }
    }
    buf ^= 1;
  }
  // D layout [d][q]: lane (fm,fq) reg r holds o for q = g*16+fm,
  // d = c4*16 + fq*4 + r. ls[g][*] all hold l[q = g*16+fm].
  if (STORE) {
    float* Ob = Oacc + (((size_t)half * NH + h) * S_LEN + qt * 256 + w * 32) * DH;
    float* Lb = Lacc + ((size_t)half * NH + h) * S_LEN + qt * 256 + w * 32;
#pragma unroll
    for (int g = 0; g < 2; ++g) {
      if (fq == 0) Lb[g * 16 + fm] = ls[g][0];
#pragma unroll
      for (int c4 = 0; c4 < 4; ++c4)
        *(float4*)(Ob + (size_t)(g * 16 + fm) * DH + c4 * 16 + fq * 4) =
            float4{o[g][c4][0], o[g][c4][1], o[g][c4][2], o[g][c4][3]};
    }
  } else {
    // fallback: atomic accumulate into shared Oacc/Lacc
    float* Ob = Oacc + ((size_t)h * S_LEN + qt * 256 + w * 32) * DH;
    float* Lb = Lacc + h * S_LEN + qt * 256 + w * 32;
#pragma unroll
    for (int g = 0; g < 2; ++g) {
      if (fq == 0) unsafeAtomicAdd(Lb + g * 16 + fm, ls[g][0]);
#pragma unroll
      for (int c4 = 0; c4 < 4; ++c4)
#pragma unroll
        for (int r = 0; r < 4; ++r)
          unsafeAtomicAdd(Ob + (size_t)(g * 16 + fm) * DH + c4 * 16 + fq * 4 + r, o[g][c4][r]);
    }
  }
}

// ---------------- combine (4-split): Ctx = bf16(sum(Oj) / sum(Lj)) ----------
__global__ __launch_bounds__(256) void combine4_kernel(const float* __restrict__ O,
                                                       const float* __restrict__ L,
                                                       u16* __restrict__ Ctx) {
  int idx = blockIdx.x * 256 + threadIdx.x;  // 1,048,576 threads
  int d4 = (idx & 15) * 4;
  int hh = (idx >> 4) & 15;
  int row = idx >> 8;
  const size_t OS = (size_t)NH * S_LEN * DH, LS = (size_t)NH * S_LEN;
  size_t ob = ((size_t)hh * S_LEN + row) * DH + d4;
  size_t lb = (size_t)hh * S_LEN + row;
  float4 a = *(const float4*)(O + ob);
  float4 b = *(const float4*)(O + OS + ob);
  float4 c = *(const float4*)(O + 2 * OS + ob);
  float4 d = *(const float4*)(O + 3 * OS + ob);
  float il = 1.0f / (L[lb] + L[LS + lb] + L[2 * LS + lb] + L[3 * LS + lb]);
  uint2 o;
  o.x = pk2((a.x + b.x + c.x + d.x) * il, (a.y + b.y + c.y + d.y) * il);
  o.y = pk2((a.z + b.z + c.z + d.z) * il, (a.w + b.w + c.w + d.w) * il);
  *(uint2*)(Ctx + (size_t)row * DM + hh * DH + d4) = o;
}

// ---------------- combine (2-split): Ctx = bf16((O0+O1) / (L0+L1)) ----------
__global__ __launch_bounds__(256) void combine2_kernel(const float* __restrict__ O0,
                                                       const float* __restrict__ O1,
                                                       const float* __restrict__ L0,
                                                       const float* __restrict__ L1,
                                                       u16* __restrict__ Ctx) {
  int idx = blockIdx.x * 256 + threadIdx.x;  // 1,048,576 threads
  int d4 = (idx & 15) * 4;
  int hh = (idx >> 4) & 15;
  int row = idx >> 8;
  size_t ob = ((size_t)hh * S_LEN + row) * DH + d4;
  float4 a = *(const float4*)(O0 + ob);
  float4 b = *(const float4*)(O1 + ob);
  float il = 1.0f / (L0[hh * S_LEN + row] + L1[hh * S_LEN + row]);
  uint2 o;
  o.x = pk2((a.x + b.x) * il, (a.y + b.y) * il);
  o.y = pk2((a.z + b.z) * il, (a.w + b.w) * il);
  *(uint2*)(Ctx + (size_t)row * DM + hh * DH + d4) = o;
}

// ---------------- combine (atomic fallback): Ctx = bf16(Oacc / Lacc) --------
__global__ __launch_bounds__(256) void combine_kernel(const float* __restrict__ Oacc,
                                                      const float* __restrict__ Lacc,
                                                      u16* __restrict__ Ctx) {
  int idx = blockIdx.x * 256 + threadIdx.x;  // 1,048,576 threads
  int d4 = (idx & 15) * 4;
  int hh = (idx >> 4) & 15;
  int row = idx >> 8;
  float4 a = *(const float4*)(Oacc + ((size_t)hh * S_LEN + row) * DH + d4);
  float il = 1.0f / Lacc[hh * S_LEN + row];
  uint2 o;
  o.x = pk2(a.x * il, a.y * il);
  o.y = pk2(a.z * il, a.w * il);
  *(uint2*)(Ctx + (size_t)row * DM + hh * DH + d4) = o;
}

extern "C" void kernel_launch(void* const* d_in, const int* in_sizes, int n_in,
                              void* d_out, int out_size, void* d_ws, size_t ws_size,
                              hipStream_t stream) {
  const float* x  = (const float*)d_in[0];
  const float* Wq = (const float*)d_in[1];
  const float* Wk = (const float*)d_in[2];
  const float* Wv = (const float*)d_in[3];
  const float* Wo = (const float*)d_in[4];
  float* out = (float*)d_out;

  const size_t MB = 1u << 20;
  char* ws = (char*)d_ws;

  if (ws_size >= 104 * MB) {
    // 4-split layout (104 MB):
    //  [0,8)   xb -> Ctx;  [8,14) wqb/wkb/wvb -> Lpart[4] (1 MB) after qkv
    //  [14,16) wob; [16,40) Qb, Kb, Vtb; [40,104) Opart [4][16][4096][64] f32
    u16* xb    = (u16*)(ws + 0 * MB);
    u16* wqb   = (u16*)(ws + 8 * MB);
    u16* wkb   = (u16*)(ws + 10 * MB);
    u16* wvb   = (u16*)(ws + 12 * MB);
    u16* wob   = (u16*)(ws + 14 * MB);
    u16* Qb    = (u16*)(ws + 16 * MB);
    u16* Kb    = (u16*)(ws + 24 * MB);
    u16* Vtb   = (u16*)(ws + 32 * MB);
    float* Op  = (float*)(ws + 40 * MB);
    float* Lp  = (float*)(ws + 8 * MB);
    u16* Ctx   = (u16*)(ws + 0 * MB);

    cvt_all<<<8192, 256, 0, stream>>>(x, Wq, Wk, Wv, Wo, xb, wqb, wkb, wvb, wob);
    qkv_gemm<<<dim3(24, 32), 256, 0, stream>>>(xb, wqb, wkb, wvb, Qb, Kb, Vtb);
    attn_kernel<1, 4><<<1024, 512, 0, stream>>>(Qb, Kb, Vtb, Op, Lp);
    combine4_kernel<<<4096, 256, 0, stream>>>(Op, Lp, Ctx);
    o_gemm<<<dim3(8, 64), 256, 0, stream>>>(Ctx, wob, out, S_LEN, DM, DM);
  } else if (ws_size >= 72 * MB) {
    // 2-split store layout (72 MB) — proven 199.3 us path
    u16* xb    = (u16*)(ws + 0 * MB);
    u16* wqb   = (u16*)(ws + 8 * MB);
    u16* wkb   = (u16*)(ws + 10 * MB);
    u16* wvb   = (u16*)(ws + 12 * MB);
    u16* wob   = (u16*)(ws + 14 * MB);
    u16* Qb    = (u16*)(ws + 16 * MB);
    u16* Kb    = (u16*)(ws + 24 * MB);
    u16* Vtb   = (u16*)(ws + 32 * MB);
    float* Op  = (float*)(ws + 40 * MB);
    float* Lp  = (float*)(ws + 8 * MB);
    u16* Ctx   = (u16*)(ws + 0 * MB);

    cvt_all<<<8192, 256, 0, stream>>>(x, Wq, Wk, Wv, Wo, xb, wqb, wkb, wvb, wob);
    qkv_gemm<<<dim3(24, 32), 256, 0, stream>>>(xb, wqb, wkb, wvb, Qb, Kb, Vtb);
    attn_kernel<1, 2><<<512, 512, 0, stream>>>(Qb, Kb, Vtb, Op, Lp);
    combine2_kernel<<<4096, 256, 0, stream>>>(Op, Op + (size_t)NH * S_LEN * DH,
                                              Lp, Lp + (size_t)NH * S_LEN, Ctx);
    o_gemm<<<dim3(8, 64), 256, 0, stream>>>(Ctx, wob, out, S_LEN, DM, DM);
  } else {
    // fallback: round-0 layout + atomic path
    u16* xb    = (u16*)(ws + 0 * MB);
    u16* wqb   = (u16*)(ws + 8 * MB);
    u16* wkb   = (u16*)(ws + 10 * MB);
    u16* wvb   = (u16*)(ws + 12 * MB);
    float* Oacc = (float*)(ws + 0 * MB);
    float* Lacc = (float*)(ws + 16 * MB);
    u16* wob   = (u16*)(ws + 17 * MB);
    u16* Qb    = (u16*)(ws + 19 * MB);
    u16* Kb    = (u16*)(ws + 27 * MB);
    u16* Vtb   = (u16*)(ws + 35 * MB);
    u16* Ctx   = (u16*)(ws + 43 * MB);

    cvt_all<<<8192, 256, 0, stream>>>(x, Wq, Wk, Wv, Wo, xb, wqb, wkb, wvb, wob);
    qkv_gemm<<<dim3(24, 32), 256, 0, stream>>>(xb, wqb, wkb, wvb, Qb, Kb, Vtb);
    zero_kernel<<<4160, 256, 0, stream>>>((float4*)Oacc);
    attn_kernel<0, 2><<<512, 512, 0, stream>>>(Qb, Kb, Vtb, Oacc, Lacc);
    combine_kernel<<<4096, 256, 0, stream>>>(Oacc, Lacc, Ctx);
    o_gemm<<<dim3(8, 64), 256, 0, stream>>>(Ctx, wob, out, S_LEN, DM, DM);
  }
}